// Round 1
// baseline (1691.970 us; speedup 1.0000x reference)
//
#include <hip/hip_runtime.h>
#include <cstdint>

#define H 128
#define VV 100
#define CC 1000
#define ER_N 250
#define EP_N 250000
#define NP_N 100000
#define NODE_IN_N 82
#define EDGE_IN_N 6

// out[N,H] = act(A[N,K] @ W[K,H] + b) ; 4 rows per block, 128 threads (1 col each)
template<int K, bool RELU>
__global__ __launch_bounds__(128) void lin_kernel(
    const float* __restrict__ A, const float* __restrict__ W,
    const float* __restrict__ b, float* __restrict__ out, int N) {
  __shared__ float sA[4][K];
  const int j = threadIdx.x;
  const int row0 = blockIdx.x * 4;
  for (int idx = j; idx < 4 * K; idx += 128) {
    int r = idx / K, c = idx - r * K;
    int rr = row0 + r;
    sA[r][c] = (rr < N) ? A[(size_t)rr * K + c] : 0.0f;
  }
  __syncthreads();
  float a0 = 0.f, a1 = 0.f, a2 = 0.f, a3 = 0.f;
#pragma unroll 4
  for (int k = 0; k < K; ++k) {
    float w = W[k * H + j];
    a0 = fmaf(sA[0][k], w, a0);
    a1 = fmaf(sA[1][k], w, a1);
    a2 = fmaf(sA[2][k], w, a2);
    a3 = fmaf(sA[3][k], w, a3);
  }
  const float bb = b[j];
  a0 += bb; a1 += bb; a2 += bb; a3 += bb;
  if (RELU) {
    a0 = fmaxf(a0, 0.f); a1 = fmaxf(a1, 0.f);
    a2 = fmaxf(a2, 0.f); a3 = fmaxf(a3, 0.f);
  }
  if (row0 + 0 < N) out[(size_t)(row0 + 0) * H + j] = a0;
  if (row0 + 1 < N) out[(size_t)(row0 + 1) * H + j] = a1;
  if (row0 + 2 < N) out[(size_t)(row0 + 2) * H + j] = a2;
  if (row0 + 3 < N) out[(size_t)(row0 + 3) * H + j] = a3;
}

// out[N,H] = relu(A[N,H] @ W[0:H] + B[N,H] @ W[H:2H] + bias) ; in-place safe (out==A)
__global__ __launch_bounds__(128) void lin2_kernel(
    const float* __restrict__ A, const float* __restrict__ B,
    const float* __restrict__ W /*[2H,H]*/, const float* __restrict__ bias,
    float* __restrict__ out, int N) {
  __shared__ float sA[4][H];
  __shared__ float sB[4][H];
  const int j = threadIdx.x;
  const int row0 = blockIdx.x * 4;
  for (int idx = j; idx < 4 * H; idx += 128) {
    int r = idx >> 7, c = idx & 127;
    int rr = row0 + r;
    sA[r][c] = (rr < N) ? A[(size_t)rr * H + c] : 0.0f;
    sB[r][c] = (rr < N) ? B[(size_t)rr * H + c] : 0.0f;
  }
  __syncthreads();
  float a0 = 0.f, a1 = 0.f, a2 = 0.f, a3 = 0.f;
#pragma unroll 4
  for (int k = 0; k < H; ++k) {
    float w1 = W[k * H + j];
    float w2 = W[(k + H) * H + j];
    a0 = fmaf(sA[0][k], w1, fmaf(sB[0][k], w2, a0));
    a1 = fmaf(sA[1][k], w1, fmaf(sB[1][k], w2, a1));
    a2 = fmaf(sA[2][k], w1, fmaf(sB[2][k], w2, a2));
    a3 = fmaf(sA[3][k], w1, fmaf(sB[3][k], w2, a3));
  }
  const float bb = bias[j];
  a0 = fmaxf(a0 + bb, 0.f); a1 = fmaxf(a1 + bb, 0.f);
  a2 = fmaxf(a2 + bb, 0.f); a3 = fmaxf(a3 + bb, 0.f);
  if (row0 + 0 < N) out[(size_t)(row0 + 0) * H + j] = a0;
  if (row0 + 1 < N) out[(size_t)(row0 + 1) * H + j] = a1;
  if (row0 + 2 < N) out[(size_t)(row0 + 2) * H + j] = a2;
  if (row0 + 3 < N) out[(size_t)(row0 + 3) * H + j] = a3;
}

// per edge: m = relu(t[src] + e @ Wb + (bias already inside t)); agg[dst] += m
__global__ __launch_bounds__(128) void edge_kernel(
    const float* __restrict__ t, const float* __restrict__ ef,
    const float* __restrict__ Wb /*[EDGE_IN,H]*/,
    const int* __restrict__ src, const int* __restrict__ dst,
    float* __restrict__ agg, int E) {
  const int j = threadIdx.x;
  const int e0 = blockIdx.x * 4;
  __shared__ float sW[EDGE_IN_N][H];
  for (int idx = j; idx < EDGE_IN_N * H; idx += 128) sW[idx / H][idx & 127] = Wb[idx];
  __syncthreads();
#pragma unroll
  for (int i = 0; i < 4; ++i) {
    int e = e0 + i;
    if (e >= E) break;
    int s = src[e], d = dst[e];
    float v = t[(size_t)s * H + j];
#pragma unroll
    for (int k = 0; k < EDGE_IN_N; ++k)
      v = fmaf(ef[(size_t)e * EDGE_IN_N + k], sW[k][j], v);
    v = fmaxf(v, 0.f);
    atomicAdd(&agg[(size_t)d * H + j], v);
  }
}

// h[c*V+v][j] -= hr[v][j]
__global__ __launch_bounds__(256) void diff_kernel(float* __restrict__ h,
                                                   const float* __restrict__ hr) {
  size_t idx = (size_t)blockIdx.x * 256 + threadIdx.x;
  if (idx < (size_t)NP_N * H) {
    int j = (int)(idx & (H - 1));
    int n = (int)(idx >> 7);
    int v = n % VV;
    h[idx] -= hr[v * H + j];
  }
}

// per candidate: g = sum_v h[c,v,:]; out = relu(g@W1+b1)@W2 + b2 + score
__global__ __launch_bounds__(128) void head_kernel(
    const float* __restrict__ h, const float* __restrict__ W1,
    const float* __restrict__ b1, const float* __restrict__ W2,
    const float* __restrict__ b2, const float* __restrict__ scores,
    float* __restrict__ out) {
  const int c = blockIdx.x;
  const int j = threadIdx.x;
  __shared__ float sg[H];
  __shared__ float red[H];
  const float* base = h + (size_t)c * VV * H + j;
  float g = 0.f;
#pragma unroll 4
  for (int v = 0; v < VV; ++v) g += base[(size_t)v * H];
  sg[j] = g;
  __syncthreads();
  float acc = b1[j];
#pragma unroll 4
  for (int k = 0; k < H; ++k) acc = fmaf(sg[k], W1[k * H + j], acc);
  acc = fmaxf(acc, 0.f) * W2[j];
  red[j] = acc;
  __syncthreads();
  for (int s = 64; s > 0; s >>= 1) {
    if (j < s) red[j] += red[j + s];
    __syncthreads();
  }
  if (j == 0) out[c] = red[0] + b2[0] + scores[c];
}

extern "C" void kernel_launch(void* const* d_in, const int* in_sizes, int n_in,
                              void* d_out, int out_size, void* d_ws, size_t ws_size,
                              hipStream_t stream) {
  const float* Xr  = (const float*)d_in[0];   // [100,82]
  const float* Ere = (const float*)d_in[1];   // [250,6]
  const float* Xp  = (const float*)d_in[2];   // [100000,82]
  const float* Epe = (const float*)d_in[3];   // [250000,6]
  const float* sc  = (const float*)d_in[4];   // [1000,1]
  const float* Wp  = (const float*)d_in[5];
  const float* bp  = (const float*)d_in[6];
  const float* Wm  = (const float*)d_in[7];   // [134,128]
  const float* bm  = (const float*)d_in[8];
  const float* Wn  = (const float*)d_in[9];   // [256,128]
  const float* bn  = (const float*)d_in[10];
  const float* Wmd = (const float*)d_in[11];
  const float* bmd = (const float*)d_in[12];
  const float* Wnd = (const float*)d_in[13];
  const float* bnd = (const float*)d_in[14];
  const float* W1  = (const float*)d_in[15];
  const float* b1  = (const float*)d_in[16];
  const float* W2  = (const float*)d_in[17];
  const float* b2  = (const float*)d_in[18];
  const int* rsrc  = (const int*)d_in[19];
  const int* rdst  = (const int*)d_in[20];
  const int* psrc  = (const int*)d_in[21];
  const int* pdst  = (const int*)d_in[22];

  float* h    = (float*)d_ws;                 // [100000,128]
  float* t    = h   + (size_t)NP_N * H;       // [100000,128]
  float* agg  = t   + (size_t)NP_N * H;       // [100000,128]
  float* hr   = agg + (size_t)NP_N * H;       // [100,128]
  float* tr   = hr  + VV * H;
  float* aggr = tr  + VV * H;

  float* out = (float*)d_out;

  const int PROD_BLK = (NP_N + 3) / 4;        // 25000
  const int REAC_BLK = (VV + 3) / 4;          // 25
  const int PEDGE_BLK = (EP_N + 3) / 4;       // 62500
  const int REDGE_BLK = (ER_N + 3) / 4;       // 63

  // input projections (shared weights)
  lin_kernel<NODE_IN_N, true><<<REAC_BLK, 128, 0, stream>>>(Xr, Wp, bp, hr, VV);
  lin_kernel<NODE_IN_N, true><<<PROD_BLK, 128, 0, stream>>>(Xp, Wp, bp, h, NP_N);

  // reactant WLN, 3 shared-weight layers
  for (int l = 0; l < 3; ++l) {
    lin_kernel<H, false><<<REAC_BLK, 128, 0, stream>>>(hr, Wm, bm, tr, VV);
    hipMemsetAsync(aggr, 0, (size_t)VV * H * sizeof(float), stream);
    edge_kernel<<<REDGE_BLK, 128, 0, stream>>>(tr, Ere, Wm + H * H, rsrc, rdst, aggr, ER_N);
    lin2_kernel<<<REAC_BLK, 128, 0, stream>>>(hr, aggr, Wn, bn, hr, VV);
  }

  // product WLN, 3 shared-weight layers
  for (int l = 0; l < 3; ++l) {
    lin_kernel<H, false><<<PROD_BLK, 128, 0, stream>>>(h, Wm, bm, t, NP_N);
    hipMemsetAsync(agg, 0, (size_t)NP_N * H * sizeof(float), stream);
    edge_kernel<<<PEDGE_BLK, 128, 0, stream>>>(t, Epe, Wm + H * H, psrc, pdst, agg, EP_N);
    lin2_kernel<<<PROD_BLK, 128, 0, stream>>>(h, agg, Wn, bn, h, NP_N);
  }

  // diff against broadcast reactant
  diff_kernel<<<((size_t)NP_N * H + 255) / 256, 256, 0, stream>>>(h, hr);

  // diff WLN, 1 layer
  lin_kernel<H, false><<<PROD_BLK, 128, 0, stream>>>(h, Wmd, bmd, t, NP_N);
  hipMemsetAsync(agg, 0, (size_t)NP_N * H * sizeof(float), stream);
  edge_kernel<<<PEDGE_BLK, 128, 0, stream>>>(t, Epe, Wmd + H * H, psrc, pdst, agg, EP_N);
  lin2_kernel<<<PROD_BLK, 128, 0, stream>>>(h, agg, Wnd, bnd, h, NP_N);

  // sum-pool + MLP head + candidate scores
  head_kernel<<<CC, 128, 0, stream>>>(h, W1, b1, W2, b2, sc, out);
}

// Round 2
// 1249.485 us; speedup vs baseline: 1.3541x; 1.3541x over previous
//
#include <hip/hip_runtime.h>
#include <cstdint>

#define H 128
#define VV 100
#define CC 1000
#define ER_N 250
#define EP_N 250000
#define NP_N 100000
#define NODE_IN_N 82
#define EDGE_IN_N 6

#define BM 64
#define BK 32
#define SA_STRIDE 36  // 36*4B = 144B row stride: keeps float4 alignment, breaks pow2

// ---------------- register-tiled fp32 GEMM: out = act(A1@W[0:H] (+ A2@W[H:2H]) + b)
// A1/A2: [N,H], W: [(HAS_A2?2H:H), H] row-major, out: [N,H]. In-place safe (out==A1/A2).
template<bool HAS_A2, bool RELU>
__global__ __launch_bounds__(256) void gemm128(
    const float* __restrict__ A1, const float* __restrict__ A2,
    const float* __restrict__ W, const float* __restrict__ bias,
    float* __restrict__ out, int N) {
  __shared__ float sW[BK][H];          // 16 KB
  __shared__ float sA[BM][SA_STRIDE];  // 9 KB
  const int tid = threadIdx.x;
  const int cg = tid & 31, rg = tid >> 5;
  const int j0 = cg * 4, r0 = rg * 8;
  const int row0 = blockIdx.x * BM;
  float acc[8][4] = {};
  const int nparts = HAS_A2 ? 2 : 1;
  for (int part = 0; part < nparts; ++part) {
    const float* A = (part == 0) ? A1 : A2;
    const float* Wp = W + (size_t)part * H * H;
    for (int kc = 0; kc < H; kc += BK) {
      __syncthreads();
      // stage W chunk [BK][H]: 1024 float4, 4 per thread, coalesced
      {
        const float4* s = (const float4*)(Wp + (size_t)kc * H);
        float4* d = (float4*)(&sW[0][0]);
#pragma unroll
        for (int i = 0; i < 4; ++i) d[tid + 256 * i] = s[tid + 256 * i];
      }
      // stage A chunk [BM][BK]: 512 float4, 2 per thread
      {
#pragma unroll
        for (int i = 0; i < 2; ++i) {
          int f = tid + 256 * i;       // 0..511
          int r = f >> 3;              // row within tile
          int kk = (f & 7) * 4;        // k within chunk
          int row = row0 + r;
          float4 v = make_float4(0.f, 0.f, 0.f, 0.f);
          if (row < N) v = *(const float4*)(A + (size_t)row * H + kc + kk);
          *(float4*)(&sA[r][kk]) = v;
        }
      }
      __syncthreads();
#pragma unroll
      for (int k4 = 0; k4 < BK; k4 += 4) {
        float wvv[4][4];
#pragma unroll
        for (int kk = 0; kk < 4; ++kk) {
          float4 w4 = *(const float4*)(&sW[k4 + kk][j0]);
          wvv[kk][0] = w4.x; wvv[kk][1] = w4.y; wvv[kk][2] = w4.z; wvv[kk][3] = w4.w;
        }
#pragma unroll
        for (int r = 0; r < 8; ++r) {
          float4 a4 = *(const float4*)(&sA[r0 + r][k4]);
          float avv[4] = {a4.x, a4.y, a4.z, a4.w};
#pragma unroll
          for (int kk = 0; kk < 4; ++kk)
#pragma unroll
            for (int c = 0; c < 4; ++c)
              acc[r][c] = fmaf(avv[kk], wvv[kk][c], acc[r][c]);
        }
      }
    }
  }
  float4 b4 = *(const float4*)(bias + j0);
  float bb[4] = {b4.x, b4.y, b4.z, b4.w};
#pragma unroll
  for (int r = 0; r < 8; ++r) {
    int row = row0 + r0 + r;
    if (row < N) {
      float o[4];
#pragma unroll
      for (int c = 0; c < 4; ++c) {
        o[c] = acc[r][c] + bb[c];
        if (RELU) o[c] = fmaxf(o[c], 0.f);
      }
      *(float4*)(out + (size_t)row * H + j0) = make_float4(o[0], o[1], o[2], o[3]);
    }
  }
}

// ---------------- CSR build (product graphs: exactly ER_N edges per graph, dst local to graph)
__global__ __launch_bounds__(256) void hist_kernel(const int* __restrict__ dst,
                                                   int* __restrict__ cnt, int E) {
  int e = blockIdx.x * 256 + threadIdx.x;
  if (e < E) atomicAdd(&cnt[dst[e]], 1);
}

// one block per graph: exclusive scan of 100 counts, base = c*ER_N
__global__ __launch_bounds__(128) void scan_kernel(const int* __restrict__ cnt,
                                                   int* __restrict__ row_ptr,
                                                   int* __restrict__ cursor) {
  __shared__ int s[128];
  const int c = blockIdx.x, tid = threadIdx.x;
  int v = (tid < VV) ? cnt[c * VV + tid] : 0;
  s[tid] = v;
  __syncthreads();
  for (int off = 1; off < 128; off <<= 1) {
    int x = (tid >= off) ? s[tid - off] : 0;
    __syncthreads();
    s[tid] += x;
    __syncthreads();
  }
  if (tid < VV) {
    int ex = c * ER_N + s[tid] - v;
    row_ptr[c * VV + tid] = ex;
    cursor[c * VV + tid] = ex;
  }
  if (c == CC - 1 && tid == 0) row_ptr[CC * VV] = CC * ER_N;
}

__global__ __launch_bounds__(256) void fill_kernel(const int* __restrict__ dst,
                                                   int* __restrict__ cursor,
                                                   int* __restrict__ eidx, int E) {
  int e = blockIdx.x * 256 + threadIdx.x;
  if (e < E) {
    int p = atomicAdd(&cursor[dst[e]], 1);
    eidx[p] = e;
  }
}

// ---------------- gather-based message aggregation (no atomics, no memset)
// agg[n][j] = sum_{e: dst=n} relu(t[src_e][j] + ef[e] @ Wb[:, j])   (bias already in t)
__global__ __launch_bounds__(256) void agg_gather(
    const float* __restrict__ t, const float* __restrict__ ef,
    const float* __restrict__ Wb /*[EDGE_IN,H]*/,
    const int* __restrict__ row_ptr, const int* __restrict__ eidx,
    const int* __restrict__ src, float* __restrict__ agg, int Nnodes) {
  __shared__ float sW[EDGE_IN_N][H];
  const int tid = threadIdx.x;
  for (int i = tid; i < EDGE_IN_N * H; i += 256) sW[i >> 7][i & 127] = Wb[i];
  __syncthreads();
  const int j = tid & 127, half = tid >> 7;
  const int base = blockIdx.x * 8;
#pragma unroll
  for (int it = 0; it < 4; ++it) {
    int n = base + it * 2 + half;
    if (n < Nnodes) {
      int e0 = row_ptr[n], e1 = row_ptr[n + 1];
      float acc = 0.f;
      for (int p = e0; p < e1; ++p) {
        int e = eidx[p];
        int s = src[e];
        float v = t[(size_t)s * H + j];
        const float* ep = ef + (size_t)e * EDGE_IN_N;
#pragma unroll
        for (int k = 0; k < EDGE_IN_N; ++k) v = fmaf(ep[k], sW[k][j], v);
        acc += fmaxf(v, 0.f);
      }
      agg[(size_t)n * H + j] = acc;
    }
  }
}

// ---------------- small reactant-path kernels (round-0, tiny cost) ----------------
template<int K, bool RELU>
__global__ __launch_bounds__(128) void lin_kernel(
    const float* __restrict__ A, const float* __restrict__ W,
    const float* __restrict__ b, float* __restrict__ out, int N) {
  __shared__ float sA[4][K];
  const int j = threadIdx.x;
  const int row0 = blockIdx.x * 4;
  for (int idx = j; idx < 4 * K; idx += 128) {
    int r = idx / K, c = idx - r * K;
    int rr = row0 + r;
    sA[r][c] = (rr < N) ? A[(size_t)rr * K + c] : 0.0f;
  }
  __syncthreads();
  float a0 = 0.f, a1 = 0.f, a2 = 0.f, a3 = 0.f;
#pragma unroll 4
  for (int k = 0; k < K; ++k) {
    float w = W[k * H + j];
    a0 = fmaf(sA[0][k], w, a0);
    a1 = fmaf(sA[1][k], w, a1);
    a2 = fmaf(sA[2][k], w, a2);
    a3 = fmaf(sA[3][k], w, a3);
  }
  const float bb = b[j];
  a0 += bb; a1 += bb; a2 += bb; a3 += bb;
  if (RELU) {
    a0 = fmaxf(a0, 0.f); a1 = fmaxf(a1, 0.f);
    a2 = fmaxf(a2, 0.f); a3 = fmaxf(a3, 0.f);
  }
  if (row0 + 0 < N) out[(size_t)(row0 + 0) * H + j] = a0;
  if (row0 + 1 < N) out[(size_t)(row0 + 1) * H + j] = a1;
  if (row0 + 2 < N) out[(size_t)(row0 + 2) * H + j] = a2;
  if (row0 + 3 < N) out[(size_t)(row0 + 3) * H + j] = a3;
}

__global__ __launch_bounds__(128) void lin2_kernel(
    const float* __restrict__ A, const float* __restrict__ B,
    const float* __restrict__ W, const float* __restrict__ bias,
    float* __restrict__ out, int N) {
  __shared__ float sA[4][H];
  __shared__ float sB[4][H];
  const int j = threadIdx.x;
  const int row0 = blockIdx.x * 4;
  for (int idx = j; idx < 4 * H; idx += 128) {
    int r = idx >> 7, c = idx & 127;
    int rr = row0 + r;
    sA[r][c] = (rr < N) ? A[(size_t)rr * H + c] : 0.0f;
    sB[r][c] = (rr < N) ? B[(size_t)rr * H + c] : 0.0f;
  }
  __syncthreads();
  float a0 = 0.f, a1 = 0.f, a2 = 0.f, a3 = 0.f;
#pragma unroll 4
  for (int k = 0; k < H; ++k) {
    float w1 = W[k * H + j];
    float w2 = W[(k + H) * H + j];
    a0 = fmaf(sA[0][k], w1, fmaf(sB[0][k], w2, a0));
    a1 = fmaf(sA[1][k], w1, fmaf(sB[1][k], w2, a1));
    a2 = fmaf(sA[2][k], w1, fmaf(sB[2][k], w2, a2));
    a3 = fmaf(sA[3][k], w1, fmaf(sB[3][k], w2, a3));
  }
  const float bb = bias[j];
  a0 = fmaxf(a0 + bb, 0.f); a1 = fmaxf(a1 + bb, 0.f);
  a2 = fmaxf(a2 + bb, 0.f); a3 = fmaxf(a3 + bb, 0.f);
  if (row0 + 0 < N) out[(size_t)(row0 + 0) * H + j] = a0;
  if (row0 + 1 < N) out[(size_t)(row0 + 1) * H + j] = a1;
  if (row0 + 2 < N) out[(size_t)(row0 + 2) * H + j] = a2;
  if (row0 + 3 < N) out[(size_t)(row0 + 3) * H + j] = a3;
}

__global__ __launch_bounds__(128) void edge_kernel(
    const float* __restrict__ t, const float* __restrict__ ef,
    const float* __restrict__ Wb, const int* __restrict__ src,
    const int* __restrict__ dst, float* __restrict__ agg, int E) {
  const int j = threadIdx.x;
  const int e0 = blockIdx.x * 4;
  __shared__ float sW[EDGE_IN_N][H];
  for (int idx = j; idx < EDGE_IN_N * H; idx += 128) sW[idx / H][idx & 127] = Wb[idx];
  __syncthreads();
#pragma unroll
  for (int i = 0; i < 4; ++i) {
    int e = e0 + i;
    if (e >= E) break;
    int s = src[e], d = dst[e];
    float v = t[(size_t)s * H + j];
#pragma unroll
    for (int k = 0; k < EDGE_IN_N; ++k)
      v = fmaf(ef[(size_t)e * EDGE_IN_N + k], sW[k][j], v);
    v = fmaxf(v, 0.f);
    atomicAdd(&agg[(size_t)d * H + j], v);
  }
}

__global__ __launch_bounds__(256) void diff_kernel(float* __restrict__ h,
                                                   const float* __restrict__ hr) {
  size_t idx = (size_t)blockIdx.x * 256 + threadIdx.x;
  if (idx < (size_t)NP_N * H) {
    int j = (int)(idx & (H - 1));
    int n = (int)(idx >> 7);
    int v = n % VV;
    h[idx] -= hr[v * H + j];
  }
}

__global__ __launch_bounds__(128) void head_kernel(
    const float* __restrict__ h, const float* __restrict__ W1,
    const float* __restrict__ b1, const float* __restrict__ W2,
    const float* __restrict__ b2, const float* __restrict__ scores,
    float* __restrict__ out) {
  const int c = blockIdx.x;
  const int j = threadIdx.x;
  __shared__ float sg[H];
  __shared__ float red[H];
  const float* base = h + (size_t)c * VV * H + j;
  float g = 0.f;
#pragma unroll 4
  for (int v = 0; v < VV; ++v) g += base[(size_t)v * H];
  sg[j] = g;
  __syncthreads();
  float acc = b1[j];
#pragma unroll 4
  for (int k = 0; k < H; ++k) acc = fmaf(sg[k], W1[k * H + j], acc);
  acc = fmaxf(acc, 0.f) * W2[j];
  red[j] = acc;
  __syncthreads();
  for (int s = 64; s > 0; s >>= 1) {
    if (j < s) red[j] += red[j + s];
    __syncthreads();
  }
  if (j == 0) out[c] = red[0] + b2[0] + scores[c];
}

extern "C" void kernel_launch(void* const* d_in, const int* in_sizes, int n_in,
                              void* d_out, int out_size, void* d_ws, size_t ws_size,
                              hipStream_t stream) {
  const float* Xr  = (const float*)d_in[0];
  const float* Ere = (const float*)d_in[1];
  const float* Xp  = (const float*)d_in[2];
  const float* Epe = (const float*)d_in[3];
  const float* sc  = (const float*)d_in[4];
  const float* Wp  = (const float*)d_in[5];
  const float* bp  = (const float*)d_in[6];
  const float* Wm  = (const float*)d_in[7];
  const float* bm  = (const float*)d_in[8];
  const float* Wn  = (const float*)d_in[9];
  const float* bn  = (const float*)d_in[10];
  const float* Wmd = (const float*)d_in[11];
  const float* bmd = (const float*)d_in[12];
  const float* Wnd = (const float*)d_in[13];
  const float* bnd = (const float*)d_in[14];
  const float* W1  = (const float*)d_in[15];
  const float* b1  = (const float*)d_in[16];
  const float* W2  = (const float*)d_in[17];
  const float* b2  = (const float*)d_in[18];
  const int* rsrc  = (const int*)d_in[19];
  const int* rdst  = (const int*)d_in[20];
  const int* psrc  = (const int*)d_in[21];
  const int* pdst  = (const int*)d_in[22];

  float* h    = (float*)d_ws;
  float* t    = h   + (size_t)NP_N * H;
  float* agg  = t   + (size_t)NP_N * H;
  float* hr   = agg + (size_t)NP_N * H;
  float* tr   = hr  + VV * H;
  float* aggr = tr  + VV * H;
  int* cnt     = (int*)(aggr + VV * H);
  int* row_ptr = cnt + NP_N;            // NP_N + 1 entries
  int* cursor  = row_ptr + NP_N + 1;
  int* eidx    = cursor + NP_N;

  float* out = (float*)d_out;

  const int GEMM_BLK = (NP_N + BM - 1) / BM;  // 1563
  const int REAC_BLK = (VV + 3) / 4;
  const int REDGE_BLK = (ER_N + 3) / 4;

  // ---- build CSR over product edges (static graph, rebuilt each call)
  hipMemsetAsync(cnt, 0, NP_N * sizeof(int), stream);
  hist_kernel<<<(EP_N + 255) / 256, 256, 0, stream>>>(pdst, cnt, EP_N);
  scan_kernel<<<CC, 128, 0, stream>>>(cnt, row_ptr, cursor);
  fill_kernel<<<(EP_N + 255) / 256, 256, 0, stream>>>(pdst, cursor, eidx, EP_N);

  // ---- input projections
  lin_kernel<NODE_IN_N, true><<<REAC_BLK, 128, 0, stream>>>(Xr, Wp, bp, hr, VV);
  lin_kernel<NODE_IN_N, true><<<(NP_N + 3) / 4, 128, 0, stream>>>(Xp, Wp, bp, h, NP_N);

  // ---- reactant WLN (tiny, 3 layers)
  for (int l = 0; l < 3; ++l) {
    lin_kernel<H, false><<<REAC_BLK, 128, 0, stream>>>(hr, Wm, bm, tr, VV);
    hipMemsetAsync(aggr, 0, (size_t)VV * H * sizeof(float), stream);
    edge_kernel<<<REDGE_BLK, 128, 0, stream>>>(tr, Ere, Wm + H * H, rsrc, rdst, aggr, ER_N);
    lin2_kernel<<<REAC_BLK, 128, 0, stream>>>(hr, aggr, Wn, bn, hr, VV);
  }

  // ---- product WLN (3 layers)
  for (int l = 0; l < 3; ++l) {
    gemm128<false, false><<<GEMM_BLK, 256, 0, stream>>>(h, nullptr, Wm, bm, t, NP_N);
    agg_gather<<<NP_N / 8, 256, 0, stream>>>(t, Epe, Wm + H * H, row_ptr, eidx, psrc, agg, NP_N);
    gemm128<true, true><<<GEMM_BLK, 256, 0, stream>>>(h, agg, Wn, bn, h, NP_N);
  }

  // ---- diff + diff WLN (1 layer)
  diff_kernel<<<((size_t)NP_N * H + 255) / 256, 256, 0, stream>>>(h, hr);
  gemm128<false, false><<<GEMM_BLK, 256, 0, stream>>>(h, nullptr, Wmd, bmd, t, NP_N);
  agg_gather<<<NP_N / 8, 256, 0, stream>>>(t, Epe, Wmd + H * H, row_ptr, eidx, psrc, agg, NP_N);
  gemm128<true, true><<<GEMM_BLK, 256, 0, stream>>>(h, agg, Wnd, bnd, h, NP_N);

  // ---- head
  head_kernel<<<CC, 128, 0, stream>>>(h, W1, b1, W2, b2, sc, out);
}

// Round 3
// 853.318 us; speedup vs baseline: 1.9828x; 1.4643x over previous
//
#include <hip/hip_runtime.h>
#include <hip/hip_bf16.h>
#include <cstdint>

#define H 128
#define VV 100
#define CC 1000
#define ER_N 250
#define EP_N 250000
#define NP_N 100000
#define NODE_IN_N 82
#define EDGE_IN_N 6

typedef short short8 __attribute__((ext_vector_type(8)));
typedef float floatx4 __attribute__((ext_vector_type(4)));
typedef __hip_bfloat16 bf16;

// ---------------- weight prep: fp32 [Ksrc x 128] -> bf16 B-fragment order ----------
// frag layout: dst[((kc*8+nt)*64+lane)*8 + j] = W[kc*32+(lane>>4)*8+j][nt*16+(lane&15)]
__global__ __launch_bounds__(256) void prep_wfrag(const float* __restrict__ W,
                                                  bf16* __restrict__ dst,
                                                  int Ksrc, int total) {
  int idx = blockIdx.x * 256 + threadIdx.x;
  if (idx >= total) return;
  int j = idx & 7, lane = (idx >> 3) & 63, nt = (idx >> 9) & 7, kc = idx >> 12;
  int k = kc * 32 + (lane >> 4) * 8 + j;
  int n = nt * 16 + (lane & 15);
  float v = (k < Ksrc) ? W[(size_t)k * H + n] : 0.f;
  dst[idx] = __float2bfloat16(v);
}

// ---------------- MFMA GEMM: out = act(A1@W (+ A2@W2nd) + b), bf16 out -------------
// 64 rows x 128 cols per block, 256 threads (4 waves; wave w owns rows w*16..w*16+15).
// A-frag: A[m=lane&15][k=quad*8+j] (verified m120); B-frag from prepped Wf;
// C/D: row=quad*4+reg, col=lane&15 (verified m89/m91).
template<int KPAD, bool A_FP32, bool HAS_A2, bool RELU>
__global__ __launch_bounds__(256) void mfma_gemm(
    const void* __restrict__ A1v, const void* __restrict__ A2v,
    const bf16* __restrict__ Wf, const float* __restrict__ bias,
    bf16* __restrict__ out, int N, int Ksrc) {
  __shared__ bf16 sA[64][136];  // +8 bf16 pad: frag reads land 2-way on banks (free)
  const int tid = threadIdx.x;
  const int lane = tid & 63, wave = tid >> 6;
  const int quad = lane >> 4, l16 = lane & 15;
  const int row0 = blockIdx.x * 64;
  floatx4 acc[8];
#pragma unroll
  for (int nt = 0; nt < 8; ++nt) acc[nt] = (floatx4){0.f, 0.f, 0.f, 0.f};
  constexpr int CHUNKS = KPAD / 32;
  constexpr int NPARTS = HAS_A2 ? 2 : 1;
  for (int part = 0; part < NPARTS; ++part) {
    __syncthreads();
    if (A_FP32) {
      const float* A = (const float*)A1v;
      for (int idx = tid; idx < 64 * KPAD; idx += 256) {
        int r = idx / KPAD, c = idx - r * KPAD;
        int row = row0 + r;
        float v = (c < Ksrc && row < N) ? A[(size_t)row * Ksrc + c] : 0.f;
        sA[r][c] = __float2bfloat16(v);
      }
    } else {
      const bf16* A = (const bf16*)(part ? A2v : A1v);
#pragma unroll
      for (int i = 0; i < 4; ++i) {
        int f = tid + 256 * i;           // 0..1023 = 64 rows x 16 groups of 8 bf16
        int r = f >> 4, g = f & 15;
        int row = row0 + r;
        float4 v = make_float4(0.f, 0.f, 0.f, 0.f);
        if (row < N) v = *(const float4*)(A + (size_t)row * H + g * 8);
        *(float4*)&sA[r][g * 8] = v;
      }
    }
    __syncthreads();
    const bf16* wp = Wf + (size_t)part * CHUNKS * 4096;
#pragma unroll
    for (int kc = 0; kc < CHUNKS; ++kc) {
      short8 a = *(const short8*)&sA[wave * 16 + l16][kc * 32 + quad * 8];
#pragma unroll
      for (int nt = 0; nt < 8; ++nt) {
        short8 b = *(const short8*)(wp + ((size_t)(kc * 8 + nt) * 64 + lane) * 8);
        acc[nt] = __builtin_amdgcn_mfma_f32_16x16x32_bf16(a, b, acc[nt], 0, 0, 0);
      }
    }
  }
  // epilogue: bias + act, stage through LDS for coalesced stores
  __syncthreads();
#pragma unroll
  for (int nt = 0; nt < 8; ++nt) {
    int col = nt * 16 + l16;
    float bb = bias[col];
#pragma unroll
    for (int r = 0; r < 4; ++r) {
      float v = acc[nt][r] + bb;
      if (RELU) v = fmaxf(v, 0.f);
      sA[wave * 16 + quad * 4 + r][col] = __float2bfloat16(v);
    }
  }
  __syncthreads();
#pragma unroll
  for (int i = 0; i < 4; ++i) {
    int f = tid + 256 * i;
    int r = f >> 4, g = f & 15;
    int row = row0 + r;
    if (row < N)
      *((float4*)(out + (size_t)row * H) + g) = *(const float4*)&sA[r][g * 8];
  }
}

// ---------------- CSR build ----------------
__global__ __launch_bounds__(256) void hist_kernel(const int* __restrict__ dst,
                                                   int* __restrict__ cnt, int E) {
  int e = blockIdx.x * 256 + threadIdx.x;
  if (e < E) atomicAdd(&cnt[dst[e]], 1);
}

__global__ __launch_bounds__(128) void scan_kernel(const int* __restrict__ cnt,
                                                   int* __restrict__ row_ptr,
                                                   int* __restrict__ cursor, int nC) {
  __shared__ int s[128];
  const int c = blockIdx.x, tid = threadIdx.x;
  int v = (tid < VV) ? cnt[c * VV + tid] : 0;
  s[tid] = v;
  __syncthreads();
  for (int off = 1; off < 128; off <<= 1) {
    int x = (tid >= off) ? s[tid - off] : 0;
    __syncthreads();
    s[tid] += x;
    __syncthreads();
  }
  if (tid < VV) {
    int ex = c * ER_N + s[tid] - v;
    row_ptr[c * VV + tid] = ex;
    cursor[c * VV + tid] = ex;
  }
  if (c == nC - 1 && tid == 0) row_ptr[nC * VV] = nC * ER_N;
}

__global__ __launch_bounds__(256) void fill_kernel(const int* __restrict__ dst,
                                                   int* __restrict__ cursor,
                                                   int* __restrict__ eidx, int E) {
  int e = blockIdx.x * 256 + threadIdx.x;
  if (e < E) {
    int p = atomicAdd(&cursor[dst[e]], 1);
    eidx[p] = e;
  }
}

// ---------------- gather aggregation (bf16 t/agg, fp32 math) ----------------
__global__ __launch_bounds__(256) void agg_gather(
    const bf16* __restrict__ t, const float* __restrict__ ef,
    const float* __restrict__ Wb /*[6,128] fp32*/,
    const int* __restrict__ row_ptr, const int* __restrict__ eidx,
    const int* __restrict__ src, bf16* __restrict__ agg, int Nnodes) {
  __shared__ float sW[EDGE_IN_N][H];
  const int tid = threadIdx.x;
  for (int i = tid; i < EDGE_IN_N * H; i += 256) sW[i >> 7][i & 127] = Wb[i];
  __syncthreads();
  const int j = tid & 127, half = tid >> 7;
  const int base = blockIdx.x * 8;
#pragma unroll
  for (int it = 0; it < 4; ++it) {
    int n = base + it * 2 + half;
    if (n < Nnodes) {
      int e0 = row_ptr[n], e1 = row_ptr[n + 1];
      float acc = 0.f;
      for (int p = e0; p < e1; ++p) {
        int e = eidx[p];
        int s = src[e];
        float v = __bfloat162float(t[(size_t)s * H + j]);
        const float* epf = ef + (size_t)e * EDGE_IN_N;
#pragma unroll
        for (int k = 0; k < EDGE_IN_N; ++k) v = fmaf(epf[k], sW[k][j], v);
        acc += fmaxf(v, 0.f);
      }
      agg[(size_t)n * H + j] = __float2bfloat16(acc);
    }
  }
}

// ---------------- diff: h[c,v,:] -= hr[v,:] (both bf16) ----------------
__global__ __launch_bounds__(256) void diff_kernel(bf16* __restrict__ h,
                                                   const bf16* __restrict__ hr) {
  size_t idx = (size_t)blockIdx.x * 256 + threadIdx.x;
  if (idx < (size_t)NP_N * H) {
    int j = (int)(idx & (H - 1));
    int n = (int)(idx >> 7);
    int v = n % VV;
    h[idx] = __float2bfloat16(__bfloat162float(h[idx]) -
                              __bfloat162float(hr[v * H + j]));
  }
}

// ---------------- head: sum-pool + MLP + scores ----------------
__global__ __launch_bounds__(128) void head_kernel(
    const bf16* __restrict__ h, const float* __restrict__ W1,
    const float* __restrict__ b1, const float* __restrict__ W2,
    const float* __restrict__ b2, const float* __restrict__ scores,
    float* __restrict__ out) {
  const int c = blockIdx.x;
  const int j = threadIdx.x;
  __shared__ float sg[H];
  __shared__ float red[H];
  const bf16* base = h + (size_t)c * VV * H + j;
  float g = 0.f;
#pragma unroll 4
  for (int v = 0; v < VV; ++v) g += __bfloat162float(base[(size_t)v * H]);
  sg[j] = g;
  __syncthreads();
  float acc = b1[j];
#pragma unroll 4
  for (int k = 0; k < H; ++k) acc = fmaf(sg[k], W1[k * H + j], acc);
  acc = fmaxf(acc, 0.f) * W2[j];
  red[j] = acc;
  __syncthreads();
  for (int s = 64; s > 0; s >>= 1) {
    if (j < s) red[j] += red[j + s];
    __syncthreads();
  }
  if (j == 0) out[c] = red[0] + b2[0] + scores[c];
}

extern "C" void kernel_launch(void* const* d_in, const int* in_sizes, int n_in,
                              void* d_out, int out_size, void* d_ws, size_t ws_size,
                              hipStream_t stream) {
  const float* Xr  = (const float*)d_in[0];
  const float* Ere = (const float*)d_in[1];
  const float* Xp  = (const float*)d_in[2];
  const float* Epe = (const float*)d_in[3];
  const float* sc  = (const float*)d_in[4];
  const float* Wp  = (const float*)d_in[5];
  const float* bp  = (const float*)d_in[6];
  const float* Wm  = (const float*)d_in[7];
  const float* bm  = (const float*)d_in[8];
  const float* Wn  = (const float*)d_in[9];
  const float* bn  = (const float*)d_in[10];
  const float* Wmd = (const float*)d_in[11];
  const float* bmd = (const float*)d_in[12];
  const float* Wnd = (const float*)d_in[13];
  const float* bnd = (const float*)d_in[14];
  const float* W1  = (const float*)d_in[15];
  const float* b1  = (const float*)d_in[16];
  const float* W2  = (const float*)d_in[17];
  const float* b2  = (const float*)d_in[18];
  const int* rsrc  = (const int*)d_in[19];
  const int* rdst  = (const int*)d_in[20];
  const int* psrc  = (const int*)d_in[21];
  const int* pdst  = (const int*)d_in[22];

  // workspace layout (bf16 tensors, then frags, then ints)
  bf16* h   = (bf16*)d_ws;                       // [100000,128]
  bf16* t   = h + (size_t)NP_N * H;
  bf16* agg = t + (size_t)NP_N * H;
  bf16* hr   = agg + (size_t)NP_N * H;           // [100,128]
  bf16* tr   = hr + VV * H;
  bf16* aggr = tr + VV * H;
  bf16* wf_proj = aggr + VV * H;                 // 96/32*4096  = 12288
  bf16* wf_msg  = wf_proj + 3 * 4096;            // 128/32*4096 = 16384
  bf16* wf_new  = wf_msg + 4 * 4096;             // 256/32*4096 = 32768
  bf16* wf_msgd = wf_new + 8 * 4096;
  bf16* wf_newd = wf_msgd + 4 * 4096;
  int* cnt     = (int*)(wf_newd + 8 * 4096);
  int* row_ptr = cnt + NP_N;                     // NP_N+1
  int* cursor  = row_ptr + NP_N + 1;
  int* eidx    = cursor + NP_N;                  // EP_N
  int* cnt_r     = eidx + EP_N;
  int* row_ptr_r = cnt_r + VV;                   // VV+1
  int* cursor_r  = row_ptr_r + VV + 1;
  int* eidx_r    = cursor_r + VV;                // ER_N

  float* out = (float*)d_out;

  const int GB = (NP_N + 63) / 64;   // 1563
  const int RB = (VV + 63) / 64;     // 2

  // ---- weight prep (B-frag bf16) ----
  prep_wfrag<<<(96 * H + 255) / 256, 256, 0, stream>>>(Wp, wf_proj, NODE_IN_N, 96 * H);
  prep_wfrag<<<(128 * H + 255) / 256, 256, 0, stream>>>(Wm, wf_msg, H, 128 * H);
  prep_wfrag<<<(256 * H + 255) / 256, 256, 0, stream>>>(Wn, wf_new, 2 * H, 256 * H);
  prep_wfrag<<<(128 * H + 255) / 256, 256, 0, stream>>>(Wmd, wf_msgd, H, 128 * H);
  prep_wfrag<<<(256 * H + 255) / 256, 256, 0, stream>>>(Wnd, wf_newd, 2 * H, 256 * H);

  // ---- CSR build (product + reactant) ----
  hipMemsetAsync(cnt, 0, NP_N * sizeof(int), stream);
  hist_kernel<<<(EP_N + 255) / 256, 256, 0, stream>>>(pdst, cnt, EP_N);
  scan_kernel<<<CC, 128, 0, stream>>>(cnt, row_ptr, cursor, CC);
  fill_kernel<<<(EP_N + 255) / 256, 256, 0, stream>>>(pdst, cursor, eidx, EP_N);
  hipMemsetAsync(cnt_r, 0, VV * sizeof(int), stream);
  hist_kernel<<<1, 256, 0, stream>>>(rdst, cnt_r, ER_N);
  scan_kernel<<<1, 128, 0, stream>>>(cnt_r, row_ptr_r, cursor_r, 1);
  fill_kernel<<<1, 256, 0, stream>>>(rdst, cursor_r, eidx_r, ER_N);

  // ---- input projections (shared weights) ----
  mfma_gemm<96, true, false, true><<<RB, 256, 0, stream>>>(
      Xr, nullptr, wf_proj, bp, hr, VV, NODE_IN_N);
  mfma_gemm<96, true, false, true><<<GB, 256, 0, stream>>>(
      Xp, nullptr, wf_proj, bp, h, NP_N, NODE_IN_N);

  // ---- reactant WLN (3 shared-weight layers) ----
  for (int l = 0; l < 3; ++l) {
    mfma_gemm<128, false, false, false><<<RB, 256, 0, stream>>>(
        hr, nullptr, wf_msg, bm, tr, VV, H);
    agg_gather<<<(VV + 7) / 8, 256, 0, stream>>>(
        tr, Ere, Wm + H * H, row_ptr_r, eidx_r, rsrc, aggr, VV);
    mfma_gemm<128, false, true, true><<<RB, 256, 0, stream>>>(
        hr, aggr, wf_new, bn, hr, VV, H);
  }

  // ---- product WLN (3 layers) ----
  for (int l = 0; l < 3; ++l) {
    mfma_gemm<128, false, false, false><<<GB, 256, 0, stream>>>(
        h, nullptr, wf_msg, bm, t, NP_N, H);
    agg_gather<<<NP_N / 8, 256, 0, stream>>>(
        t, Epe, Wm + H * H, row_ptr, eidx, psrc, agg, NP_N);
    mfma_gemm<128, false, true, true><<<GB, 256, 0, stream>>>(
        h, agg, wf_new, bn, h, NP_N, H);
  }

  // ---- diff + diff WLN (1 layer) ----
  diff_kernel<<<((size_t)NP_N * H + 255) / 256, 256, 0, stream>>>(h, hr);
  mfma_gemm<128, false, false, false><<<GB, 256, 0, stream>>>(
      h, nullptr, wf_msgd, bmd, t, NP_N, H);
  agg_gather<<<NP_N / 8, 256, 0, stream>>>(
      t, Epe, Wmd + H * H, row_ptr, eidx, psrc, agg, NP_N);
  mfma_gemm<128, false, true, true><<<GB, 256, 0, stream>>>(
      h, agg, wf_newd, bnd, h, NP_N, H);

  // ---- head ----
  head_kernel<<<CC, 128, 0, stream>>>(h, W1, b1, W2, b2, sc, out);
}